// Round 1
// baseline (3435.881 us; speedup 1.0000x reference)
//
#include <hip/hip_runtime.h>
#include <cstdint>

// Problem constants (fixed by the reference):
#define H_DIM 4096
#define I_DIM 14336
#define M_TOT 8192        // B*S = 4*2048
#define NI_DIM (2 * I_DIM) // interleaved gate/up N = 28672

typedef __bf16 bf16_t;
typedef bf16_t bf16x8_t __attribute__((ext_vector_type(8)));
typedef float f32x4_t __attribute__((ext_vector_type(4)));

#define AS1 __attribute__((address_space(1)))
#define AS3 __attribute__((address_space(3)))

// fp32 -> bf16 bits, round-to-nearest-even
static __device__ __forceinline__ unsigned short f2bf(float f) {
  union { float f; unsigned int u; } v; v.f = f;
  unsigned int r = ((v.u >> 16) & 1u) + 0x7FFFu;
  return (unsigned short)((v.u + r) >> 16);
}

// async global->LDS, 16B per lane. lds ptr wave-uniform; HW writes base+lane*16.
static __device__ __forceinline__ void gl2lds16(const void* g, void* l) {
  __builtin_amdgcn_global_load_lds((AS1 void*)(void*)g, (AS3 void*)l, 16, 0, 0);
}

// ---------------------------------------------------------------------------
// Kernel 1: x fp32 -> bf16 (grid-stride, float4 in / ushort4 out)
// ---------------------------------------------------------------------------
__global__ void k_cvt_x(const float* __restrict__ x,
                        unsigned short* __restrict__ xb, long n4) {
  long i = (long)blockIdx.x * blockDim.x + threadIdx.x;
  const long stride = (long)gridDim.x * blockDim.x;
  for (; i < n4; i += stride) {
    float4 v = ((const float4*)x)[i];
    ushort4 o;
    o.x = f2bf(v.x); o.y = f2bf(v.y); o.z = f2bf(v.z); o.w = f2bf(v.w);
    ((ushort4*)xb)[i] = o;
  }
}

// ---------------------------------------------------------------------------
// Kernel 2: dequant + transpose.  w [K][N] int32, s [K/128][N] fp32
//           -> wt [n_out(n)][K] bf16   (64x64 tile per block, 256 threads)
// ioff < 0 : n_out = n  (plain transpose)
// ioff >= 0: n_out = (n>>4)*32 + (n&15) + ioff   (16-col gate/up interleave)
// ---------------------------------------------------------------------------
__global__ void k_dequant_t(const int* __restrict__ w, const float* __restrict__ s,
                            unsigned short* __restrict__ wt, int K, int N,
                            int ioff) {
  __shared__ __align__(16) float tile[64 * 68];
  const int n0 = blockIdx.x * 64;
  const int k0 = blockIdx.y * 64;
  const int t = threadIdx.x;
  const int tx = t & 15;
  const int ty = t >> 4;
#pragma unroll
  for (int i = 0; i < 4; ++i) {
    const long gk = k0 + i * 16 + ty;
    const int4 wv = *(const int4*)(w + gk * N + (n0 + tx * 4));
    const float4 sv = *(const float4*)(s + (gk >> 7) * (long)N + (n0 + tx * 4));
    float4 o;
    o.x = (float)wv.x * sv.x;
    o.y = (float)wv.y * sv.y;
    o.z = (float)wv.z * sv.z;
    o.w = (float)wv.w * sv.w;
    *(float4*)(&tile[(i * 16 + ty) * 68 + tx * 4]) = o;
  }
  __syncthreads();
  const int nl = t >> 2;
  const int kc = (t & 3) << 4;
  unsigned int pk[8];
#pragma unroll
  for (int j = 0; j < 8; ++j) {
    unsigned int lo = f2bf(tile[(kc + 2 * j) * 68 + nl]);
    unsigned int hi = f2bf(tile[(kc + 2 * j + 1) * 68 + nl]);
    pk[j] = lo | (hi << 16);
  }
  const int n = n0 + nl;
  const long orow = (ioff < 0) ? (long)n
                               : (long)(((n >> 4) << 5) + (n & 15) + ioff);
  const long base = orow * K + (k0 + kc);
  uint4* dst = (uint4*)(wt + base);
  dst[0] = make_uint4(pk[0], pk[1], pk[2], pk[3]);
  dst[1] = make_uint4(pk[4], pk[5], pk[6], pk[7]);
}

// ---------------------------------------------------------------------------
// Pipelined GEMM template.  BM=256, BN=128, BK=64, 512 threads = 8 waves
// (4 M-waves x 2 N-waves, each 64x64 out, acc[4][4]).
// LDS: 3 buffers x (A 256x64 + B 128x64) bf16 = 144 KB, prefetch distance 2,
// counted s_waitcnt vmcnt(6) at K-tile boundaries (never 0 in steady state),
// raw s_barrier (no implicit vmcnt drain), XOR bank-swizzle (T2) via
// pre-swizzled global source (rule #21), setprio around MFMA clusters (T5).
// EPI=1: B is gate/up 16-col interleaved, out = silu(g)*u bf16 [M][I_DIM].
// EPI=2: plain fp32 out [M][H_DIM].
// ---------------------------------------------------------------------------
template <int KDIM, int EPI>
__global__ __launch_bounds__(512, 1) void k_gemm_pipe(
    const unsigned short* __restrict__ A,   // [M][KDIM] bf16
    const unsigned short* __restrict__ B,   // [Nrows][KDIM] bf16 (row = out col)
    void* __restrict__ Cout, int Ntiles) {
  __shared__ __align__(16) unsigned short lds[3 * 24576];  // 144 KB
  constexpr int KT = KDIM / 64;

  // Block swizzle: XCD chunking (nwg % 8 == 0 for both shapes), then
  // GROUP_M=16 supertiles so concurrent blocks form a 16x16 (mt,nt) window.
  const int nwg = 32 * Ntiles;   // Mtiles = 32 always (8192/256)
  int id = blockIdx.x;
  id = (id & 7) * (nwg >> 3) + (id >> 3);
  const int per = 16 * Ntiles;
  const int grp = id / per;
  const int wi = id - grp * per;
  const int mt = grp * 16 + (wi & 15);
  const int nt = wi >> 4;
  const long m0 = (long)mt * 256;
  const long n0 = (long)nt * 128;

  const int t = threadIdx.x;
  const int lane = t & 63;
  const int wave = t >> 6;
  const int wm = wave >> 1;  // 0..3, 64 rows each
  const int wn = wave & 1;   // 0..1, 64 B-rows each

  // ---- staging: linear LDS dest, inverse-swizzled global source ----
  // physical byte p in tile: row = p>>7; logical col = (p&127) ^ ((row&7)<<4)
  const int srow = t >> 3;                              // 0..63 per round
  const int scol = (((t & 7) ^ (srow & 7)) << 3);       // ushort col, swizzled
  const unsigned short* gA[4];
  const unsigned short* gB[2];
#pragma unroll
  for (int r = 0; r < 4; ++r)
    gA[r] = A + (m0 + r * 64 + srow) * (long)KDIM + scol;
#pragma unroll
  for (int r = 0; r < 2; ++r)
    gB[r] = B + (n0 + r * 64 + srow) * (long)KDIM + scol;
  unsigned short* sbase = &lds[wave * 512];  // + buf*24576 + round*4096

  // ---- fragment LDS offsets (ushort), ks0; ks1 = ^32 ----
  // read at physical: row*64 + (logical_col ^ ((row&7)<<3))  [ushort units]
  const int colb = ((lane >> 4) ^ (lane & 7)) << 3;
  int aoff[4], boff[4];
#pragma unroll
  for (int mi = 0; mi < 4; ++mi)
    aoff[mi] = (wm * 64 + mi * 16 + (lane & 15)) * 64 + colb;
#pragma unroll
  for (int ni = 0; ni < 4; ++ni)
    boff[ni] = 16384 + (wn * 64 + ni * 16 + (lane & 15)) * 64 + colb;

  auto stage3A = [&](int kt2, int bs) {  // A rounds 0..2
    const long ko = (long)kt2 * 64;
    unsigned short* d = sbase + bs * 24576;
    gl2lds16(gA[0] + ko, d);
    gl2lds16(gA[1] + ko, d + 4096);
    gl2lds16(gA[2] + ko, d + 8192);
  };
  auto stage1A2B = [&](int kt2, int bs) {  // A round 3 + B rounds 0,1
    const long ko = (long)kt2 * 64;
    unsigned short* d = sbase + bs * 24576;
    gl2lds16(gA[3] + ko, d + 12288);
    gl2lds16(gB[0] + ko, d + 16384);
    gl2lds16(gB[1] + ko, d + 20480);
  };

  f32x4_t acc[4][4];
  const f32x4_t fz = {0.f, 0.f, 0.f, 0.f};
#pragma unroll
  for (int mi = 0; mi < 4; ++mi)
#pragma unroll
    for (int ni = 0; ni < 4; ++ni) acc[mi][ni] = fz;

  // prologue: stage K-tiles 0 and 1 (12 loads outstanding / wave)
  stage3A(0, 0); stage1A2B(0, 0);
  stage3A(1, 1); stage1A2B(1, 1);

  int bi = 0;
  for (int kt = 0; kt < KT; ++kt) {
    // tile kt landed iff all but newest 6 loads (tile kt+1) complete
    if (kt != KT - 1)
      asm volatile("s_waitcnt vmcnt(6)" ::: "memory");
    else
      asm volatile("s_waitcnt vmcnt(0)" ::: "memory");
    __builtin_amdgcn_s_barrier();  // all waves' loads for tile kt visible;
                                   // all reads of buffer bs (tile kt-1) done

    const unsigned short* lb = &lds[bi * 24576];
    const int bs = (bi == 0) ? 2 : bi - 1;  // (bi+2)%3 : buffer for tile kt+2
    const bool pre = (kt + 2 < KT);

    bf16x8_t af[4], bfv[4];
    // ---- phase A: ks0 ----
#pragma unroll
    for (int mi = 0; mi < 4; ++mi) af[mi] = *(const bf16x8_t*)(lb + aoff[mi]);
#pragma unroll
    for (int ni = 0; ni < 4; ++ni) bfv[ni] = *(const bf16x8_t*)(lb + boff[ni]);
    if (pre) stage3A(kt + 2, bs);
    __builtin_amdgcn_s_barrier();
    asm volatile("s_waitcnt lgkmcnt(0)" ::: "memory");
    __builtin_amdgcn_sched_barrier(0);
    __builtin_amdgcn_s_setprio(1);
#pragma unroll
    for (int mi = 0; mi < 4; ++mi)
#pragma unroll
      for (int ni = 0; ni < 4; ++ni)
        acc[mi][ni] = __builtin_amdgcn_mfma_f32_16x16x32_bf16(
            af[mi], bfv[ni], acc[mi][ni], 0, 0, 0);
    __builtin_amdgcn_s_setprio(0);

    // ---- phase B: ks1 (same buffer, no barrier needed before reads) ----
#pragma unroll
    for (int mi = 0; mi < 4; ++mi)
      af[mi] = *(const bf16x8_t*)(lb + (aoff[mi] ^ 32));
#pragma unroll
    for (int ni = 0; ni < 4; ++ni)
      bfv[ni] = *(const bf16x8_t*)(lb + (boff[ni] ^ 32));
    if (pre) stage1A2B(kt + 2, bs);
    __builtin_amdgcn_s_barrier();
    asm volatile("s_waitcnt lgkmcnt(0)" ::: "memory");
    __builtin_amdgcn_sched_barrier(0);
    __builtin_amdgcn_s_setprio(1);
#pragma unroll
    for (int mi = 0; mi < 4; ++mi)
#pragma unroll
      for (int ni = 0; ni < 4; ++ni)
        acc[mi][ni] = __builtin_amdgcn_mfma_f32_16x16x32_bf16(
            af[mi], bfv[ni], acc[mi][ni], 0, 0, 0);
    __builtin_amdgcn_s_setprio(0);

    bi = (bi == 2) ? 0 : bi + 1;
  }

  // ---- epilogue.  C/D layout: col = lane&15, row = (lane>>4)*4 + r ----
  const long mr0 = m0 + wm * 64 + ((lane >> 4) << 2);
  if constexpr (EPI == 1) {
    // interleaved: ni pair (2p, 2p+1) = gate/up of the same 16 true cols
    unsigned short* h = (unsigned short*)Cout;
    const int col0 = (int)(n0 >> 1) + wn * 32 + (lane & 15);
#pragma unroll
    for (int mi = 0; mi < 4; ++mi) {
#pragma unroll
      for (int p = 0; p < 2; ++p) {
        const long c = col0 + p * 16;
#pragma unroll
        for (int r = 0; r < 4; ++r) {
          const float gg = acc[mi][2 * p][r];
          const float uu = acc[mi][2 * p + 1][r];
          const float sg = gg / (1.0f + __expf(-gg));
          h[(mr0 + mi * 16 + r) * (long)I_DIM + c] = f2bf(sg * uu);
        }
      }
    }
  } else {
    float* o = (float*)Cout;
    const int col0 = (int)n0 + wn * 64 + (lane & 15);
#pragma unroll
    for (int mi = 0; mi < 4; ++mi)
#pragma unroll
      for (int ni = 0; ni < 4; ++ni)
#pragma unroll
        for (int r = 0; r < 4; ++r)
          o[(mr0 + mi * 16 + r) * (long)H_DIM + (col0 + ni * 16)] =
              acc[mi][ni][r];
  }
}

// ---------------------------------------------------------------------------
// Launch.  ws layout (peak exactly 512 MiB):
//   xb   [M][H]        bf16 @ 0        ( 64 MiB)
//   w01t [2I][H] intlv bf16 @ 64 MiB   (224 MiB)
//   h    [M][I]        bf16 @ 288 MiB  (224 MiB)
//   w2t  [H][I]        bf16 @ 0        (112 MiB)  <- aliases xb+w01t after gemm1
// ---------------------------------------------------------------------------
extern "C" void kernel_launch(void* const* d_in, const int* in_sizes, int n_in,
                              void* d_out, int out_size, void* d_ws, size_t ws_size,
                              hipStream_t stream) {
  const float* x  = (const float*)d_in[0];
  const int* w0   = (const int*)d_in[1];
  const int* w1   = (const int*)d_in[2];
  const int* w2   = (const int*)d_in[3];
  const float* s0 = (const float*)d_in[4];
  const float* s1 = (const float*)d_in[5];
  const float* s2 = (const float*)d_in[6];
  float* out = (float*)d_out;

  char* p = (char*)d_ws;
  unsigned short* xb   = (unsigned short*)p;
  unsigned short* w01t = (unsigned short*)(p + (long)M_TOT * H_DIM * 2);
  unsigned short* hb   = (unsigned short*)(p + (long)M_TOT * H_DIM * 2 +
                                           (long)NI_DIM * H_DIM * 2);
  unsigned short* w2t  = (unsigned short*)p;  // reuse after gemm1

  k_cvt_x<<<8192, 256, 0, stream>>>(x, xb, (long)M_TOT * H_DIM / 4);

  // gate/up dequant+transpose into 16-col interleaved buffer
  k_dequant_t<<<dim3(I_DIM / 64, H_DIM / 64), 256, 0, stream>>>(
      w0, s0, w01t, H_DIM, I_DIM, 0);
  k_dequant_t<<<dim3(I_DIM / 64, H_DIM / 64), 256, 0, stream>>>(
      w1, s1, w01t, H_DIM, I_DIM, 16);

  k_gemm_pipe<H_DIM, 1><<<(M_TOT / 256) * (NI_DIM / 128), 512, 0, stream>>>(
      xb, w01t, hb, NI_DIM / 128);

  k_dequant_t<<<dim3(H_DIM / 64, I_DIM / 64), 256, 0, stream>>>(
      w2, s2, w2t, I_DIM, H_DIM, -1);

  k_gemm_pipe<I_DIM, 2><<<(M_TOT / 256) * (H_DIM / 128), 512, 0, stream>>>(
      hb, w2t, out, H_DIM / 128);
}

// Round 2
// 2992.440 us; speedup vs baseline: 1.1482x; 1.1482x over previous
//
#include <hip/hip_runtime.h>
#include <cstdint>

// Problem constants (fixed by the reference):
#define H_DIM 4096
#define I_DIM 14336
#define M_TOT 8192        // B*S = 4*2048
#define NI_DIM (2 * I_DIM) // interleaved gate/up N = 28672

typedef __bf16 bf16_t;
typedef bf16_t bf16x8_t __attribute__((ext_vector_type(8)));
typedef float f32x4_t __attribute__((ext_vector_type(4)));

#define AS1 __attribute__((address_space(1)))
#define AS3 __attribute__((address_space(3)))

// fp32 -> bf16 bits, round-to-nearest-even
static __device__ __forceinline__ unsigned short f2bf(float f) {
  union { float f; unsigned int u; } v; v.f = f;
  unsigned int r = ((v.u >> 16) & 1u) + 0x7FFFu;
  return (unsigned short)((v.u + r) >> 16);
}

// async global->LDS, 16B per lane. lds ptr wave-uniform; HW writes base+lane*16.
static __device__ __forceinline__ void gl2lds16(const void* g, void* l) {
  __builtin_amdgcn_global_load_lds((AS1 void*)(void*)g, (AS3 void*)l, 16, 0, 0);
}

// ---------------------------------------------------------------------------
// Kernel 1: x fp32 -> bf16 (grid-stride, float4 in / ushort4 out)
// ---------------------------------------------------------------------------
__global__ void k_cvt_x(const float* __restrict__ x,
                        unsigned short* __restrict__ xb, long n4) {
  long i = (long)blockIdx.x * blockDim.x + threadIdx.x;
  const long stride = (long)gridDim.x * blockDim.x;
  for (; i < n4; i += stride) {
    float4 v = ((const float4*)x)[i];
    ushort4 o;
    o.x = f2bf(v.x); o.y = f2bf(v.y); o.z = f2bf(v.z); o.w = f2bf(v.w);
    ((ushort4*)xb)[i] = o;
  }
}

// ---------------------------------------------------------------------------
// Kernel 2: dequant + transpose.  w [K][N] int32, s [K/128][N] fp32
//           -> wt [n_out(n)][K] bf16   (64x64 tile per block, 256 threads)
// ioff < 0 : n_out = n  (plain transpose)
// ioff >= 0: n_out = (n>>4)*32 + (n&15) + ioff   (16-col gate/up interleave)
// ---------------------------------------------------------------------------
__global__ void k_dequant_t(const int* __restrict__ w, const float* __restrict__ s,
                            unsigned short* __restrict__ wt, int K, int N,
                            int ioff) {
  __shared__ __align__(16) float tile[64 * 68];
  const int n0 = blockIdx.x * 64;
  const int k0 = blockIdx.y * 64;
  const int t = threadIdx.x;
  const int tx = t & 15;
  const int ty = t >> 4;
#pragma unroll
  for (int i = 0; i < 4; ++i) {
    const long gk = k0 + i * 16 + ty;
    const int4 wv = *(const int4*)(w + gk * N + (n0 + tx * 4));
    const float4 sv = *(const float4*)(s + (gk >> 7) * (long)N + (n0 + tx * 4));
    float4 o;
    o.x = (float)wv.x * sv.x;
    o.y = (float)wv.y * sv.y;
    o.z = (float)wv.z * sv.z;
    o.w = (float)wv.w * sv.w;
    *(float4*)(&tile[(i * 16 + ty) * 68 + tx * 4]) = o;
  }
  __syncthreads();
  const int nl = t >> 2;
  const int kc = (t & 3) << 4;
  unsigned int pk[8];
#pragma unroll
  for (int j = 0; j < 8; ++j) {
    unsigned int lo = f2bf(tile[(kc + 2 * j) * 68 + nl]);
    unsigned int hi = f2bf(tile[(kc + 2 * j + 1) * 68 + nl]);
    pk[j] = lo | (hi << 16);
  }
  const int n = n0 + nl;
  const long orow = (ioff < 0) ? (long)n
                               : (long)(((n >> 4) << 5) + (n & 15) + ioff);
  const long base = orow * K + (k0 + kc);
  uint4* dst = (uint4*)(wt + base);
  dst[0] = make_uint4(pk[0], pk[1], pk[2], pk[3]);
  dst[1] = make_uint4(pk[4], pk[5], pk[6], pk[7]);
}

// ---------------------------------------------------------------------------
// 8-phase pipelined GEMM (m201-template port).  BM=BN=256, BK=64, 512 thr =
// 8 waves (2M x 4N), each wave owns 128x64 (acc[8][4]).  LDS 128 KB =
// 2 buffers x {A0,A1,B0,B1} half-tiles of [128][64] bf16.
// Per K-tile: 4 phases, each {ds_read subtile | stage 1 half-tile (2 x
// global_load_lds) | barrier | lgkm0 | setprio(1) 16 MFMA setprio(0) |
// barrier}.  Counted vmcnt(4) once per K-tile (never 0 in steady state).
// Hazard discipline: B-halves of buf[t&1] are last read in phase1 ->
// B(t+2) staged into them at phases 2/3; A-halves of buf[(t+1)&1] were last
// read in tile t-1 phase2 -> A(t+1) staged at phases 0/1.
// XOR swizzle: 16B chunk c of row r holds logical chunk c^(r&7)
// (linear LDS dest + pre-swizzled global source; swizzled ds_read addr).
// EPI=1: B gate/up 16-col interleaved, out = silu(g)*u bf16 [M][I_DIM].
// EPI=2: plain fp32 out [M][H_DIM].
// ---------------------------------------------------------------------------
template <int KDIM, int EPI>
__global__ __launch_bounds__(512, 2) void k_gemm8(
    const unsigned short* __restrict__ A,   // [M][KDIM] bf16
    const unsigned short* __restrict__ B,   // [Nrows][KDIM] bf16 (row = out col)
    void* __restrict__ Cout, int Ntiles) {
  __shared__ __align__(16) unsigned short lds[65536];  // 128 KB
  constexpr int KT = KDIM / 64;

  // XCD chunking (nwg%8==0 for both shapes) + GROUP_M=16 supertiles.
  const int nwg = 32 * Ntiles;   // Mtiles = 8192/256 = 32
  int id = blockIdx.x;
  id = (id & 7) * (nwg >> 3) + (id >> 3);
  const int per = 16 * Ntiles;
  const int grp = id / per;
  const int wi = id - grp * per;
  const int mt = grp * 16 + (wi & 15);
  const int nt = wi >> 4;
  const long m0 = (long)mt * 256;
  const long n0 = (long)nt * 256;

  const int t = threadIdx.x;
  const int lane = t & 63;
  const int wave = t >> 6;
  const int wm = wave >> 2;  // 0..1 : 128 rows each
  const int wn = wave & 3;   // 0..3 : 64 cols each

  // ---- staging: linear LDS dest, inverse-swizzled global source ----
  const int srow = lane >> 3;                        // 0..7
  const int scol = ((lane & 7) ^ srow) << 3;         // ushort col, pre-swizzled
  const unsigned short* pA = A + (m0 + wave * 16 + srow) * (long)KDIM + scol;
  const unsigned short* pB = B + (n0 + wave * 16 + srow) * (long)KDIM + scol;
  const int ldst = wave * 1024;  // wave's 16 rows within a half-tile (ushorts)

  // ---- fragment LDS read offsets (ushort units) ----
  const int lr = lane & 15;
  const int pch = ((lane >> 4) ^ (lane & 7)) << 3;   // ks=0 physical chunk
  int aof[4], bof[4];
#pragma unroll
  for (int mi = 0; mi < 4; ++mi)
    aof[mi] = wm * 8192 + (mi * 16 + lr) * 64 + pch;            // A-sub0
#pragma unroll
  for (int nj = 0; nj < 4; ++nj)
    bof[nj] = 16384 + (wn >> 1) * 8192 +
              ((wn & 1) * 64 + nj * 16 + lr) * 64 + pch;

  auto stgA = [&](int tile, int half, int buf) {
    const long go = (long)half * 128 * KDIM + (long)tile * 64;
    unsigned short* d = &lds[buf * 32768 + half * 8192 + ldst];
    gl2lds16(pA + go, d);
    gl2lds16(pA + go + 8 * (long)KDIM, d + 512);
  };
  auto stgB = [&](int tile, int half, int buf) {
    const long go = (long)half * 128 * KDIM + (long)tile * 64;
    unsigned short* d = &lds[buf * 32768 + 16384 + half * 8192 + ldst];
    gl2lds16(pB + go, d);
    gl2lds16(pB + go + 8 * (long)KDIM, d + 512);
  };

  f32x4_t acc[8][4];
  const f32x4_t fz = {0.f, 0.f, 0.f, 0.f};
#pragma unroll
  for (int mi = 0; mi < 8; ++mi)
#pragma unroll
    for (int nj = 0; nj < 4; ++nj) acc[mi][nj] = fz;

  // prologue: B(0), A(0) into buf0; B(1) into buf1.  vmcnt(4) -> tile0 landed.
  stgB(0, 0, 0); stgB(0, 1, 0);
  stgA(0, 0, 0); stgA(0, 1, 0);
  stgB(1, 0, 1); stgB(1, 1, 1);
  asm volatile("s_waitcnt vmcnt(4)" ::: "memory");
  __builtin_amdgcn_s_barrier();

  bf16x8_t af[4][2], b0[2][2], b1[2][2];

  for (int kt = 0; kt < KT; ++kt) {
    const int cb = kt & 1;
    const unsigned short* lb = &lds[cb * 32768];
    const bool pa = (kt + 1 < KT);
    const bool pb = (kt + 2 < KT);

    // ---- phase 0: read A-sub0 + B-sub0; stage A0(t+1); MFMA q(0,0) ----
#pragma unroll
    for (int mi = 0; mi < 4; ++mi) {
      af[mi][0] = *(const bf16x8_t*)(lb + aof[mi]);
      af[mi][1] = *(const bf16x8_t*)(lb + (aof[mi] ^ 32));
    }
#pragma unroll
    for (int nj = 0; nj < 2; ++nj) {
      b0[nj][0] = *(const bf16x8_t*)(lb + bof[nj]);
      b0[nj][1] = *(const bf16x8_t*)(lb + (bof[nj] ^ 32));
    }
    if (pa) stgA(kt + 1, 0, cb ^ 1);
    __builtin_amdgcn_s_barrier();
    asm volatile("s_waitcnt lgkmcnt(0)" ::: "memory");
    __builtin_amdgcn_sched_barrier(0);
    __builtin_amdgcn_s_setprio(1);
#pragma unroll
    for (int mi = 0; mi < 4; ++mi)
#pragma unroll
      for (int nj = 0; nj < 2; ++nj)
#pragma unroll
        for (int ks = 0; ks < 2; ++ks)
          acc[mi][nj] = __builtin_amdgcn_mfma_f32_16x16x32_bf16(
              af[mi][ks], b0[nj][ks], acc[mi][nj], 0, 0, 0);
    __builtin_amdgcn_s_setprio(0);
    __builtin_amdgcn_s_barrier();

    // ---- phase 1: read B-sub1; stage A1(t+1); MFMA q(0,1) ----
#pragma unroll
    for (int nj = 0; nj < 2; ++nj) {
      b1[nj][0] = *(const bf16x8_t*)(lb + bof[2 + nj]);
      b1[nj][1] = *(const bf16x8_t*)(lb + (bof[2 + nj] ^ 32));
    }
    if (pa) stgA(kt + 1, 1, cb ^ 1);
    __builtin_amdgcn_s_barrier();
    asm volatile("s_waitcnt lgkmcnt(0)" ::: "memory");
    __builtin_amdgcn_sched_barrier(0);
    __builtin_amdgcn_s_setprio(1);
#pragma unroll
    for (int mi = 0; mi < 4; ++mi)
#pragma unroll
      for (int nj = 0; nj < 2; ++nj)
#pragma unroll
        for (int ks = 0; ks < 2; ++ks)
          acc[mi][2 + nj] = __builtin_amdgcn_mfma_f32_16x16x32_bf16(
              af[mi][ks], b1[nj][ks], acc[mi][2 + nj], 0, 0, 0);
    __builtin_amdgcn_s_setprio(0);
    __builtin_amdgcn_s_barrier();

    // ---- phase 2: read A-sub1; stage B0(t+2); MFMA q(1,1) ----
#pragma unroll
    for (int mi = 0; mi < 4; ++mi) {
      af[mi][0] = *(const bf16x8_t*)(lb + (aof[mi] + 4096));
      af[mi][1] = *(const bf16x8_t*)(lb + ((aof[mi] + 4096) ^ 32));
    }
    if (pb) stgB(kt + 2, 0, cb);
    __builtin_amdgcn_s_barrier();
    asm volatile("s_waitcnt lgkmcnt(0)" ::: "memory");
    __builtin_amdgcn_sched_barrier(0);
    __builtin_amdgcn_s_setprio(1);
#pragma unroll
    for (int mi = 0; mi < 4; ++mi)
#pragma unroll
      for (int nj = 0; nj < 2; ++nj)
#pragma unroll
        for (int ks = 0; ks < 2; ++ks)
          acc[4 + mi][2 + nj] = __builtin_amdgcn_mfma_f32_16x16x32_bf16(
              af[mi][ks], b1[nj][ks], acc[4 + mi][2 + nj], 0, 0, 0);
    __builtin_amdgcn_s_setprio(0);
    __builtin_amdgcn_s_barrier();

    // ---- phase 3: stage B1(t+2); MFMA q(1,0); counted vmcnt; barrier ----
    if (pb) stgB(kt + 2, 1, cb);
    __builtin_amdgcn_s_barrier();
    __builtin_amdgcn_s_setprio(1);
#pragma unroll
    for (int mi = 0; mi < 4; ++mi)
#pragma unroll
      for (int nj = 0; nj < 2; ++nj)
#pragma unroll
        for (int ks = 0; ks < 2; ++ks)
          acc[4 + mi][nj] = __builtin_amdgcn_mfma_f32_16x16x32_bf16(
              af[mi][ks], b0[nj][ks], acc[4 + mi][nj], 0, 0, 0);
    __builtin_amdgcn_s_setprio(0);
    if (pb)
      asm volatile("s_waitcnt vmcnt(4)" ::: "memory");
    else if (pa)
      asm volatile("s_waitcnt vmcnt(0)" ::: "memory");
    __builtin_amdgcn_s_barrier();
  }

  // ---- epilogue.  C/D layout: col = lane&15, row = (lane>>4)*4 + r ----
  const long mr0 = m0 + wm * 128 + ((lane >> 4) << 2);
  if constexpr (EPI == 1) {
    // interleaved: nj pair (2k, 2k+1) = gate/up of the same 16 true cols
    unsigned short* h = (unsigned short*)Cout;
    const long col0 = (n0 >> 1) + wn * 32 + (lane & 15);
#pragma unroll
    for (int mi = 0; mi < 8; ++mi) {
#pragma unroll
      for (int k = 0; k < 2; ++k) {
        const long c = col0 + k * 16;
#pragma unroll
        for (int r = 0; r < 4; ++r) {
          const float gg = acc[mi][2 * k][r];
          const float uu = acc[mi][2 * k + 1][r];
          const float sg = gg / (1.0f + __expf(-gg));
          h[(mr0 + mi * 16 + r) * (long)I_DIM + c] = f2bf(sg * uu);
        }
      }
    }
  } else {
    float* o = (float*)Cout;
    const long col0 = n0 + wn * 64 + (lane & 15);
#pragma unroll
    for (int mi = 0; mi < 8; ++mi)
#pragma unroll
      for (int nj = 0; nj < 4; ++nj)
#pragma unroll
        for (int r = 0; r < 4; ++r)
          o[(mr0 + mi * 16 + r) * (long)H_DIM + (col0 + nj * 16)] =
              acc[mi][nj][r];
  }
}

// ---------------------------------------------------------------------------
// Launch.  ws layout (peak exactly 512 MiB):
//   xb   [M][H]        bf16 @ 0        ( 64 MiB)
//   w01t [2I][H] intlv bf16 @ 64 MiB   (224 MiB)
//   h    [M][I]        bf16 @ 288 MiB  (224 MiB)
//   w2t  [H][I]        bf16 @ 0        (112 MiB)  <- aliases xb+w01t after gemm1
// ---------------------------------------------------------------------------
extern "C" void kernel_launch(void* const* d_in, const int* in_sizes, int n_in,
                              void* d_out, int out_size, void* d_ws, size_t ws_size,
                              hipStream_t stream) {
  const float* x  = (const float*)d_in[0];
  const int* w0   = (const int*)d_in[1];
  const int* w1   = (const int*)d_in[2];
  const int* w2   = (const int*)d_in[3];
  const float* s0 = (const float*)d_in[4];
  const float* s1 = (const float*)d_in[5];
  const float* s2 = (const float*)d_in[6];
  float* out = (float*)d_out;

  char* p = (char*)d_ws;
  unsigned short* xb   = (unsigned short*)p;
  unsigned short* w01t = (unsigned short*)(p + (long)M_TOT * H_DIM * 2);
  unsigned short* hb   = (unsigned short*)(p + (long)M_TOT * H_DIM * 2 +
                                           (long)NI_DIM * H_DIM * 2);
  unsigned short* w2t  = (unsigned short*)p;  // reuse after gemm1

  k_cvt_x<<<8192, 256, 0, stream>>>(x, xb, (long)M_TOT * H_DIM / 4);

  // gate/up dequant+transpose into 16-col interleaved buffer
  k_dequant_t<<<dim3(I_DIM / 64, H_DIM / 64), 256, 0, stream>>>(
      w0, s0, w01t, H_DIM, I_DIM, 0);
  k_dequant_t<<<dim3(I_DIM / 64, H_DIM / 64), 256, 0, stream>>>(
      w1, s1, w01t, H_DIM, I_DIM, 16);

  k_gemm8<H_DIM, 1><<<(M_TOT / 256) * (NI_DIM / 256), 512, 0, stream>>>(
      xb, w01t, hb, NI_DIM / 256);

  k_dequant_t<<<dim3(H_DIM / 64, I_DIM / 64), 256, 0, stream>>>(
      w2, s2, w2t, I_DIM, H_DIM, -1);

  k_gemm8<I_DIM, 2><<<(M_TOT / 256) * (H_DIM / 256), 512, 0, stream>>>(
      hb, w2t, out, H_DIM / 256);
}

// Round 3
// 2967.210 us; speedup vs baseline: 1.1579x; 1.0085x over previous
//
#include <hip/hip_runtime.h>
#include <cstdint>

// Problem constants (fixed by the reference):
#define H_DIM 4096
#define I_DIM 14336
#define M_TOT 8192        // B*S = 4*2048
#define NI_DIM (2 * I_DIM) // interleaved gate/up N = 28672

typedef __bf16 bf16_t;
typedef bf16_t bf16x8_t __attribute__((ext_vector_type(8)));
typedef float f32x4_t __attribute__((ext_vector_type(4)));

#define AS1 __attribute__((address_space(1)))
#define AS3 __attribute__((address_space(3)))

// fp32 -> bf16 bits, round-to-nearest-even
static __device__ __forceinline__ unsigned short f2bf(float f) {
  union { float f; unsigned int u; } v; v.f = f;
  unsigned int r = ((v.u >> 16) & 1u) + 0x7FFFu;
  return (unsigned short)((v.u + r) >> 16);
}

// async global->LDS, 16B per lane. lds ptr wave-uniform; HW writes base+lane*16.
static __device__ __forceinline__ void gl2lds16(const void* g, void* l) {
  __builtin_amdgcn_global_load_lds((AS1 void*)(void*)g, (AS3 void*)l, 16, 0, 0);
}

// ---------------------------------------------------------------------------
// Kernel 1: x fp32 -> bf16 (grid-stride, float4 in / ushort4 out)
// ---------------------------------------------------------------------------
__global__ void k_cvt_x(const float* __restrict__ x,
                        unsigned short* __restrict__ xb, long n4) {
  long i = (long)blockIdx.x * blockDim.x + threadIdx.x;
  const long stride = (long)gridDim.x * blockDim.x;
  for (; i < n4; i += stride) {
    float4 v = ((const float4*)x)[i];
    ushort4 o;
    o.x = f2bf(v.x); o.y = f2bf(v.y); o.z = f2bf(v.z); o.w = f2bf(v.w);
    ((ushort4*)xb)[i] = o;
  }
}

// ---------------------------------------------------------------------------
// Kernel 2: dequant + transpose.  w [K][N] int32, s [K/128][N] fp32
//           -> wt [n_out(n)][K] bf16   (64x64 tile per block, 256 threads)
// ioff < 0 : n_out = n  (plain transpose)
// ioff >= 0: n_out = (n>>4)*32 + (n&15) + ioff   (16-col gate/up interleave)
// ---------------------------------------------------------------------------
__global__ void k_dequant_t(const int* __restrict__ w, const float* __restrict__ s,
                            unsigned short* __restrict__ wt, int K, int N,
                            int ioff) {
  __shared__ __align__(16) float tile[64 * 68];
  const int n0 = blockIdx.x * 64;
  const int k0 = blockIdx.y * 64;
  const int t = threadIdx.x;
  const int tx = t & 15;
  const int ty = t >> 4;
#pragma unroll
  for (int i = 0; i < 4; ++i) {
    const long gk = k0 + i * 16 + ty;
    const int4 wv = *(const int4*)(w + gk * N + (n0 + tx * 4));
    const float4 sv = *(const float4*)(s + (gk >> 7) * (long)N + (n0 + tx * 4));
    float4 o;
    o.x = (float)wv.x * sv.x;
    o.y = (float)wv.y * sv.y;
    o.z = (float)wv.z * sv.z;
    o.w = (float)wv.w * sv.w;
    *(float4*)(&tile[(i * 16 + ty) * 68 + tx * 4]) = o;
  }
  __syncthreads();
  const int nl = t >> 2;
  const int kc = (t & 3) << 4;
  unsigned int pk[8];
#pragma unroll
  for (int j = 0; j < 8; ++j) {
    unsigned int lo = f2bf(tile[(kc + 2 * j) * 68 + nl]);
    unsigned int hi = f2bf(tile[(kc + 2 * j + 1) * 68 + nl]);
    pk[j] = lo | (hi << 16);
  }
  const int n = n0 + nl;
  const long orow = (ioff < 0) ? (long)n
                               : (long)(((n >> 4) << 5) + (n & 15) + ioff);
  const long base = orow * K + (k0 + kc);
  uint4* dst = (uint4*)(wt + base);
  dst[0] = make_uint4(pk[0], pk[1], pk[2], pk[3]);
  dst[1] = make_uint4(pk[4], pk[5], pk[6], pk[7]);
}

// ---------------------------------------------------------------------------
// Slip-scheduled pipelined GEMM.  BM=BN=256, BK=64, 512 thr = 8 waves
// (2M x 4N), each wave owns 128x64 (acc[8][4]).  LDS 128 KB = 2 buffers x
// {A0,A1,B0,B1} half-tiles of [128][64] bf16.
// Per K-tile only TWO barriers:
//   bar2 (after q00/q01): all waves' B-reads returned -> stgB(t+2) may
//        overwrite this buffer's B-halves.
//   bar1 (tile end, after counted vmcnt(4)): tile t+1 fully landed, and all
//        waves' A-reads of the tile drained (each wave lgkm-waited before
//        its q11/q10) -> next tile's stgA may overwrite.
// ds_read->MFMA waits are compiler-counted lgkmcnt (precise, dependency-
// tracked); only gl2lds->ds_read needs the explicit asm vmcnt ("memory"
// clobber also fences hoisting across barriers).  A1 reads issue between
// q00 and q01 so their latency hides under q01's MFMAs.  Counted vmcnt(4)
// once per K-tile; never 0 in steady state.
// XOR swizzle: 16B chunk c of row r holds logical chunk c^(r&7)
// (linear LDS dest + pre-swizzled global source; swizzled ds_read addr).
// EPI=1: B gate/up 16-col interleaved, out = silu(g)*u bf16 [M][I_DIM].
// EPI=2: plain fp32 out [M][H_DIM].
// ---------------------------------------------------------------------------
template <int KDIM, int EPI>
__global__ __launch_bounds__(512, 2) void k_gemm8(
    const unsigned short* __restrict__ A,   // [M][KDIM] bf16
    const unsigned short* __restrict__ B,   // [Nrows][KDIM] bf16 (row = out col)
    void* __restrict__ Cout, int Ntiles) {
  __shared__ __align__(16) unsigned short lds[65536];  // 128 KB
  constexpr int KT = KDIM / 64;

  // XCD chunking (nwg%8==0 for both shapes) + GROUP_M=16 supertiles.
  const int nwg = 32 * Ntiles;   // Mtiles = 8192/256 = 32
  int id = blockIdx.x;
  id = (id & 7) * (nwg >> 3) + (id >> 3);
  const int per = 16 * Ntiles;
  const int grp = id / per;
  const int wi = id - grp * per;
  const int mt = grp * 16 + (wi & 15);
  const int nt = wi >> 4;
  const long m0 = (long)mt * 256;
  const long n0 = (long)nt * 256;

  const int t = threadIdx.x;
  const int lane = t & 63;
  const int wave = t >> 6;
  const int wm = wave >> 2;  // 0..1 : 128 rows each
  const int wn = wave & 3;   // 0..3 : 64 cols each

  // ---- staging: linear LDS dest, inverse-swizzled global source ----
  const int srow = lane >> 3;                        // 0..7
  const int scol = ((lane & 7) ^ srow) << 3;         // ushort col, pre-swizzled
  const unsigned short* pA = A + (m0 + wave * 16 + srow) * (long)KDIM + scol;
  const unsigned short* pB = B + (n0 + wave * 16 + srow) * (long)KDIM + scol;
  const int ldst = wave * 1024;  // wave's 16 rows within a half-tile (ushorts)

  // ---- fragment LDS read offsets (ushort units) ----
  const int lr = lane & 15;
  const int pch = ((lane >> 4) ^ (lane & 7)) << 3;   // ks=0 physical chunk
  int aof[4], bof[4];
#pragma unroll
  for (int mi = 0; mi < 4; ++mi)
    aof[mi] = wm * 8192 + (mi * 16 + lr) * 64 + pch;            // A-sub0
#pragma unroll
  for (int nj = 0; nj < 4; ++nj)
    bof[nj] = 16384 + (wn >> 1) * 8192 +
              ((wn & 1) * 64 + nj * 16 + lr) * 64 + pch;

  auto stgA = [&](int tile, int half, int buf) {
    const long go = (long)half * 128 * KDIM + (long)tile * 64;
    unsigned short* d = &lds[buf * 32768 + half * 8192 + ldst];
    gl2lds16(pA + go, d);
    gl2lds16(pA + go + 8 * (long)KDIM, d + 512);
  };
  auto stgB = [&](int tile, int half, int buf) {
    const long go = (long)half * 128 * KDIM + (long)tile * 64;
    unsigned short* d = &lds[buf * 32768 + 16384 + half * 8192 + ldst];
    gl2lds16(pB + go, d);
    gl2lds16(pB + go + 8 * (long)KDIM, d + 512);
  };

  f32x4_t acc[8][4];
  const f32x4_t fz = {0.f, 0.f, 0.f, 0.f};
#pragma unroll
  for (int mi = 0; mi < 8; ++mi)
#pragma unroll
    for (int nj = 0; nj < 4; ++nj) acc[mi][nj] = fz;

  // prologue: B(0), A(0) into buf0; B(1) into buf1.  vmcnt(4) -> tile0 landed.
  stgB(0, 0, 0); stgB(0, 1, 0);
  stgA(0, 0, 0); stgA(0, 1, 0);
  stgB(1, 0, 1); stgB(1, 1, 1);
  asm volatile("s_waitcnt vmcnt(4)" ::: "memory");
  __builtin_amdgcn_s_barrier();

  for (int kt = 0; kt < KT; ++kt) {
    const int cb = kt & 1;
    const unsigned short* lb = &lds[cb * 32768];
    const bool pa = (kt + 1 < KT);
    const bool pb = (kt + 2 < KT);

    bf16x8_t af0[4][2], af1[4][2], b0[2][2], b1[2][2];

    // ---- issue reads: A-sub0 (8), B-sub0 (4), B-sub1 (4); stage A(t+1) ----
#pragma unroll
    for (int mi = 0; mi < 4; ++mi) {
      af0[mi][0] = *(const bf16x8_t*)(lb + aof[mi]);
      af0[mi][1] = *(const bf16x8_t*)(lb + (aof[mi] ^ 32));
    }
#pragma unroll
    for (int nj = 0; nj < 2; ++nj) {
      b0[nj][0] = *(const bf16x8_t*)(lb + bof[nj]);
      b0[nj][1] = *(const bf16x8_t*)(lb + (bof[nj] ^ 32));
    }
#pragma unroll
    for (int nj = 0; nj < 2; ++nj) {
      b1[nj][0] = *(const bf16x8_t*)(lb + bof[2 + nj]);
      b1[nj][1] = *(const bf16x8_t*)(lb + (bof[2 + nj] ^ 32));
    }
    if (pa) { stgA(kt + 1, 0, cb ^ 1); stgA(kt + 1, 1, cb ^ 1); }
    __builtin_amdgcn_sched_barrier(0);

    // ---- q00: acc[0..3][0..1] += af0 x b0 (compiler-counted lgkm wait) ----
    __builtin_amdgcn_s_setprio(1);
#pragma unroll
    for (int mi = 0; mi < 4; ++mi)
#pragma unroll
      for (int nj = 0; nj < 2; ++nj)
#pragma unroll
        for (int ks = 0; ks < 2; ++ks)
          acc[mi][nj] = __builtin_amdgcn_mfma_f32_16x16x32_bf16(
              af0[mi][ks], b0[nj][ks], acc[mi][nj], 0, 0, 0);
    __builtin_amdgcn_s_setprio(0);
    __builtin_amdgcn_sched_barrier(0);

    // ---- issue A-sub1 reads (8); latency hides under q01 ----
#pragma unroll
    for (int mi = 0; mi < 4; ++mi) {
      af1[mi][0] = *(const bf16x8_t*)(lb + (aof[mi] + 4096));
      af1[mi][1] = *(const bf16x8_t*)(lb + ((aof[mi] + 4096) ^ 32));
    }
    __builtin_amdgcn_sched_barrier(0);

    // ---- q01: acc[0..3][2..3] += af0 x b1 ----
    __builtin_amdgcn_s_setprio(1);
#pragma unroll
    for (int mi = 0; mi < 4; ++mi)
#pragma unroll
      for (int nj = 0; nj < 2; ++nj)
#pragma unroll
        for (int ks = 0; ks < 2; ++ks)
          acc[mi][2 + nj] = __builtin_amdgcn_mfma_f32_16x16x32_bf16(
              af0[mi][ks], b1[nj][ks], acc[mi][2 + nj], 0, 0, 0);
    __builtin_amdgcn_s_setprio(0);

    // ---- bar2: all waves' B reads returned -> safe to overwrite B-halves --
    __builtin_amdgcn_s_barrier();
    if (pb) { stgB(kt + 2, 0, cb); stgB(kt + 2, 1, cb); }
    __builtin_amdgcn_sched_barrier(0);

    // ---- q11 then q10: acc[4..7][*] += af1 x {b1,b0} ----
    __builtin_amdgcn_s_setprio(1);
#pragma unroll
    for (int mi = 0; mi < 4; ++mi)
#pragma unroll
      for (int nj = 0; nj < 2; ++nj)
#pragma unroll
        for (int ks = 0; ks < 2; ++ks)
          acc[4 + mi][2 + nj] = __builtin_amdgcn_mfma_f32_16x16x32_bf16(
              af1[mi][ks], b1[nj][ks], acc[4 + mi][2 + nj], 0, 0, 0);
#pragma unroll
    for (int mi = 0; mi < 4; ++mi)
#pragma unroll
      for (int nj = 0; nj < 2; ++nj)
#pragma unroll
        for (int ks = 0; ks < 2; ++ks)
          acc[4 + mi][nj] = __builtin_amdgcn_mfma_f32_16x16x32_bf16(
              af1[mi][ks], b0[nj][ks], acc[4 + mi][nj], 0, 0, 0);
    __builtin_amdgcn_s_setprio(0);

    // ---- counted vmcnt: tile t+1 (A(t+1)+B(t+1)) landed; bar1 tile end ----
    if (pb)
      asm volatile("s_waitcnt vmcnt(4)" ::: "memory");
    else if (pa)
      asm volatile("s_waitcnt vmcnt(0)" ::: "memory");
    __builtin_amdgcn_s_barrier();
  }

  // ---- epilogue.  C/D layout: col = lane&15, row = (lane>>4)*4 + r ----
  const long mr0 = m0 + wm * 128 + ((lane >> 4) << 2);
  if constexpr (EPI == 1) {
    // interleaved: nj pair (2k, 2k+1) = gate/up of the same 16 true cols
    unsigned short* h = (unsigned short*)Cout;
    const long col0 = (n0 >> 1) + wn * 32 + (lane & 15);
#pragma unroll
    for (int mi = 0; mi < 8; ++mi) {
#pragma unroll
      for (int k = 0; k < 2; ++k) {
        const long c = col0 + k * 16;
#pragma unroll
        for (int r = 0; r < 4; ++r) {
          const float gg = acc[mi][2 * k][r];
          const float uu = acc[mi][2 * k + 1][r];
          const float sg = gg / (1.0f + __expf(-gg));
          h[(mr0 + mi * 16 + r) * (long)I_DIM + c] = f2bf(sg * uu);
        }
      }
    }
  } else {
    float* o = (float*)Cout;
    const long col0 = n0 + wn * 64 + (lane & 15);
#pragma unroll
    for (int mi = 0; mi < 8; ++mi)
#pragma unroll
      for (int nj = 0; nj < 4; ++nj)
#pragma unroll
        for (int r = 0; r < 4; ++r)
          o[(mr0 + mi * 16 + r) * (long)H_DIM + (col0 + nj * 16)] =
              acc[mi][nj][r];
  }
}

// ---------------------------------------------------------------------------
// Launch.  ws layout (peak exactly 512 MiB):
//   xb   [M][H]        bf16 @ 0        ( 64 MiB)
//   w01t [2I][H] intlv bf16 @ 64 MiB   (224 MiB)
//   h    [M][I]        bf16 @ 288 MiB  (224 MiB)
//   w2t  [H][I]        bf16 @ 0        (112 MiB)  <- aliases xb+w01t after gemm1
// ---------------------------------------------------------------------------
extern "C" void kernel_launch(void* const* d_in, const int* in_sizes, int n_in,
                              void* d_out, int out_size, void* d_ws, size_t ws_size,
                              hipStream_t stream) {
  const float* x  = (const float*)d_in[0];
  const int* w0   = (const int*)d_in[1];
  const int* w1   = (const int*)d_in[2];
  const int* w2   = (const int*)d_in[3];
  const float* s0 = (const float*)d_in[4];
  const float* s1 = (const float*)d_in[5];
  const float* s2 = (const float*)d_in[6];
  float* out = (float*)d_out;

  char* p = (char*)d_ws;
  unsigned short* xb   = (unsigned short*)p;
  unsigned short* w01t = (unsigned short*)(p + (long)M_TOT * H_DIM * 2);
  unsigned short* hb   = (unsigned short*)(p + (long)M_TOT * H_DIM * 2 +
                                           (long)NI_DIM * H_DIM * 2);
  unsigned short* w2t  = (unsigned short*)p;  // reuse after gemm1

  k_cvt_x<<<8192, 256, 0, stream>>>(x, xb, (long)M_TOT * H_DIM / 4);

  // gate/up dequant+transpose into 16-col interleaved buffer
  k_dequant_t<<<dim3(I_DIM / 64, H_DIM / 64), 256, 0, stream>>>(
      w0, s0, w01t, H_DIM, I_DIM, 0);
  k_dequant_t<<<dim3(I_DIM / 64, H_DIM / 64), 256, 0, stream>>>(
      w1, s1, w01t, H_DIM, I_DIM, 16);

  k_gemm8<H_DIM, 1><<<(M_TOT / 256) * (NI_DIM / 256), 512, 0, stream>>>(
      xb, w01t, hb, NI_DIM / 256);

  k_dequant_t<<<dim3(H_DIM / 64, I_DIM / 64), 256, 0, stream>>>(
      w2, s2, w2t, I_DIM, H_DIM, -1);

  k_gemm8<I_DIM, 2><<<(M_TOT / 256) * (H_DIM / 256), 512, 0, stream>>>(
      hb, w2t, out, H_DIM / 256);
}